// Round 4
// baseline (461.218 us; speedup 1.0000x reference)
//
#include <hip/hip_runtime.h>
#include <hip/hip_bf16.h>
#include <cstddef>

// Problem constants: B=4, N=512, FD=AD=256, PD=128, DP=64
// out[b,q] = softmax_k( (Q[b,q]·K[b,k] + bias[b,q,k]) / 16 ) · vsum[b,k]
//   bias[b,i,j] = rn*(dot(D[b,i,j,:],gw) - mu*sum_gw) + bconst   (gw = g_p*(W_pt@W_ph))
//   vsum[b,k]   = rn_F·(F[k]·(g_f⊙wv) − mu_F·Σ(g_f⊙wv)) + Σ(b_f⊙wv),  wv = rowsum(Wv)
//
// Workspace layout (floats):
#define OFF_GW    0          // 64   : g_p * (W_pt @ W_ph)
#define OFF_SC    320        // 2    : sum_gw, bconst
#define OFF_VSUM  384        // 2048 : vsum[b,k]
#define OFF_Q     2432       // 524288 : Q [2048][256]
#define OFF_K     526720     // 524288 : K [2048][256]
// total ~4.2 MB of d_ws

typedef float v4f __attribute__((ext_vector_type(4)));

// ---------------- K1: LN(F)+Q,K projection | vsum | consts (one launch) ----
// blocks 0-511   : projection. rowgroup g = bid>>1 (8 rows), col half h = bid&1,
//                  threads 0-127 -> Wq cols, 128-255 -> Wk cols.
// blocks 512-575 : vsum. block v covers F rows 32v..32v+31; computes wv itself.
// block  576     : gw / sum_gw / bconst (consumed only by KB — no intra-kernel dep).
__global__ __launch_bounds__(256) void k1_fused(
    const float* __restrict__ F, const float* __restrict__ Wq,
    const float* __restrict__ Wk, const float* __restrict__ Wv,
    const float* __restrict__ g_f, const float* __restrict__ b_f,
    const float* __restrict__ g_p, const float* __restrict__ b_p,
    const float* __restrict__ W_pt, const float* __restrict__ b_pt,
    const float* __restrict__ W_ph, float* __restrict__ ws) {
  int t = threadIdx.x;
  int bid = blockIdx.x;

  if (bid < 512) {  // ---------------- projection ----------------
    __shared__ __align__(16) float fn[8][260];
    __shared__ float smu[8], srn[8];
    int g = bid >> 1, h = bid & 1;
    int row0 = g * 8;
    const float* Fp = F + (size_t)row0 * 256;
#pragma unroll
    for (int k = 0; k < 8; ++k) fn[k][t] = Fp[k * 256 + t];
    __syncthreads();
    int r = t >> 5, l32 = t & 31;
    float s1 = 0.f, s2 = 0.f;
#pragma unroll
    for (int m = 0; m < 8; ++m) {
      float x = fn[r][l32 + 32 * m];
      s1 += x;
      s2 += x * x;
    }
    for (int m = 16; m >= 1; m >>= 1) {
      s1 += __shfl_xor(s1, m);
      s2 += __shfl_xor(s2, m);
    }
    if (l32 == 0) {
      float mu = s1 * (1.f / 256.f);
      float var = s2 * (1.f / 256.f) - mu * mu;
      smu[r] = mu;
      srn[r] = rsqrtf(var + 1e-3f);
    }
    __syncthreads();
    float gf = g_f[t], bf = b_f[t];
#pragma unroll
    for (int k = 0; k < 8; ++k)
      fn[k][t] = (fn[k][t] - smu[k]) * srn[k] * gf + bf;
    __syncthreads();
    int matsel = t >> 7;
    int col = h * 128 + (t & 127);
    const float* W = matsel ? Wk : Wq;
    float acc[8] = {0, 0, 0, 0, 0, 0, 0, 0};
#pragma unroll 2
    for (int f = 0; f < 256; f += 4) {
      float w0 = W[(f + 0) * 256 + col];
      float w1 = W[(f + 1) * 256 + col];
      float w2 = W[(f + 2) * 256 + col];
      float w3 = W[(f + 3) * 256 + col];
#pragma unroll
      for (int k = 0; k < 8; ++k) {
        v4f x = *(const v4f*)(&fn[k][f]);  // ds_read_b128 broadcast
        acc[k] = fmaf(x.w, w3,
                 fmaf(x.z, w2, fmaf(x.y, w1, fmaf(x.x, w0, acc[k]))));
      }
    }
    float* Out = ws + (matsel ? OFF_K : OFF_Q) + (size_t)row0 * 256 + col;
#pragma unroll
    for (int k = 0; k < 8; ++k) Out[k * 256] = acc[k];

  } else if (bid < 576) {  // ---------------- vsum ----------------
    __shared__ float wv_s[256];
    __shared__ float u_s[256];
    __shared__ float sc_s[2];
    int vb = bid - 512;
    int w = t >> 6, l = t & 63;
    // wv rowsums: wave w handles Wv rows 64w..64w+63 (coalesced + shfl reduce)
    for (int rr = 0; rr < 64; ++rr) {
      int row = 64 * w + rr;
      float s = 0.f;
#pragma unroll
      for (int j = 0; j < 4; ++j) s += Wv[row * 256 + l + 64 * j];
      for (int m = 32; m >= 1; m >>= 1) s += __shfl_xor(s, m);
      if (l == 0) wv_s[row] = s;
    }
    __syncthreads();
    u_s[t] = g_f[t] * wv_s[t];
    __syncthreads();
    if (w == 0) {
      float a1 = u_s[l] + u_s[l + 64] + u_s[l + 128] + u_s[l + 192];
      float a2 = b_f[l] * wv_s[l] + b_f[l + 64] * wv_s[l + 64] +
                 b_f[l + 128] * wv_s[l + 128] + b_f[l + 192] * wv_s[l + 192];
      for (int m = 32; m >= 1; m >>= 1) {
        a1 += __shfl_xor(a1, m);
        a2 += __shfl_xor(a2, m);
      }
      if (l == 0) {
        sc_s[0] = a1;  // Σ g_f·wv
        sc_s[1] = a2;  // Σ b_f·wv
      }
    }
    __syncthreads();
    float sgu = sc_s[0], sbv = sc_s[1];
    // rows 32vb..32vb+31; wave w does 8 rows
    for (int rr = 0; rr < 8; ++rr) {
      int row = vb * 32 + w * 8 + rr;
      float s1 = 0.f, s2 = 0.f, sw = 0.f;
#pragma unroll
      for (int j = 0; j < 4; ++j) {
        float x = F[(size_t)row * 256 + l + 64 * j];
        s1 += x;
        s2 += x * x;
        sw += x * u_s[l + 64 * j];
      }
      for (int m = 32; m >= 1; m >>= 1) {
        s1 += __shfl_xor(s1, m);
        s2 += __shfl_xor(s2, m);
        sw += __shfl_xor(sw, m);
      }
      if (l == 0) {
        float mu = s1 * (1.f / 256.f);
        float var = s2 * (1.f / 256.f) - mu * mu;
        float rn = rsqrtf(var + 1e-3f);
        ws[OFF_VSUM + row] = rn * (sw - mu * sgu) + sbv;
      }
    }

  } else {  // ---------------- gw / sc consts (for KB) ----------------
    __shared__ float wc_s[64];
    __shared__ float wph_s[128];
    if (t < 128) wph_s[t] = W_ph[t];
    __syncthreads();
    int c = t >> 2, sub = t & 3;  // 4 lanes per channel c
    float wc = 0.f;
#pragma unroll
    for (int j = 0; j < 32; ++j)
      wc += W_pt[c * 128 + sub * 32 + j] * wph_s[sub * 32 + j];
    wc += __shfl_xor(wc, 1);
    wc += __shfl_xor(wc, 2);
    if (sub == 0) {
      wc_s[c] = wc;
      ws[OFF_GW + c] = g_p[c] * wc;
    }
    __syncthreads();
    if (t == 0) {
      float sg = 0.f, bc = 0.f;
      for (int cc = 0; cc < 64; ++cc) {
        sg += g_p[cc] * wc_s[cc];
        bc += b_p[cc] * wc_s[cc];
      }
      for (int p = 0; p < 128; ++p) bc += b_pt[p] * wph_s[p];
      ws[OFF_SC] = sg;
      ws[OFF_SC + 1] = bc;
    }
  }
}

// ---------------- KB: fused pair-bias + QK^T + softmax + ·vsum -------------
// 512 blocks = (b, 4-q-row tile). Each block streams its own 512 KB of D
// (bias LN, nontemporal), adds QK^T/16, softmaxes per row, dots with vsum.
__global__ __launch_bounds__(256) void kb_bias_attn(
    const float* __restrict__ D, const float* __restrict__ ws,
    float* __restrict__ out) {
  __shared__ float4 Qs4[4][64];
  __shared__ float Sx[4][512];
  __shared__ float vs[512];
  int t = threadIdx.x;
  int b = blockIdx.x >> 7;      // 128 tiles per batch
  int tile = blockIdx.x & 127;
  int q0 = tile * 4;
  int rowbase = b * 512 + q0;   // global q row
  float* qsf = (float*)Qs4;
#pragma unroll
  for (int k = 0; k < 4; ++k)
    qsf[k * 256 + t] = ws[OFF_Q + (size_t)(rowbase + k) * 256 + t];
  vs[t] = ws[OFF_VSUM + b * 512 + t];
  vs[t + 256] = ws[OFF_VSUM + b * 512 + 256 + t];
  float sum_gw = ws[OFF_SC];
  float bconst = ws[OFF_SC + 1];
  int qq = t & 3;
  float4 g[4];
#pragma unroll
  for (int j = 0; j < 4; ++j) g[j] = ((const float4*)(ws + OFF_GW))[qq * 4 + j];

  // Phase A: bias for 4 q-rows x 512 k. 4 lanes per (q,k) entry; 32 passes.
  int e4 = t >> 2;  // 0..63
  const float* Dbase = D + (size_t)rowbase * 512 * 64;
#pragma unroll 4
  for (int pi = 0; pi < 32; ++pi) {
    int rr = pi >> 3;
    int kk = (pi & 7) * 64 + e4;
    const v4f* dp =
        (const v4f*)(Dbase + ((size_t)rr * 512 + kk) * 64 + qq * 16);
    float s1 = 0.f, s2 = 0.f, sw = 0.f;
#pragma unroll
    for (int j = 0; j < 4; ++j) {
      v4f x = __builtin_nontemporal_load(dp + j);  // one-touch stream
      s1 += x.x + x.y + x.z + x.w;
      s2 += x.x * x.x + x.y * x.y + x.z * x.z + x.w * x.w;
      sw += x.x * g[j].x + x.y * g[j].y + x.z * g[j].z + x.w * g[j].w;
    }
    s1 += __shfl_xor(s1, 1);
    s2 += __shfl_xor(s2, 1);
    sw += __shfl_xor(sw, 1);
    s1 += __shfl_xor(s1, 2);
    s2 += __shfl_xor(s2, 2);
    sw += __shfl_xor(sw, 2);
    if (qq == 0) {
      float mu = s1 * (1.f / 64.f);
      float var = s2 * (1.f / 64.f) - mu * mu;
      float rn = rsqrtf(var + 1e-3f);
      Sx[rr][kk] = (rn * (sw - mu * sum_gw) + bconst) * 0.0625f;
    }
  }
  __syncthreads();

  // Phase B: QK^T/16 added into Sx. Thread t owns k-cols t and t+256.
  const float* Kg = ws + OFF_K;
  const float4* K0p = (const float4*)(Kg + (size_t)(b * 512 + t) * 256);
  const float4* K1p = (const float4*)(Kg + (size_t)(b * 512 + 256 + t) * 256);
  float a0[4] = {0, 0, 0, 0}, a1[4] = {0, 0, 0, 0};
#pragma unroll 4
  for (int f = 0; f < 64; ++f) {
    float4 kv0 = K0p[f];
    float4 kv1 = K1p[f];
#pragma unroll
    for (int rr = 0; rr < 4; ++rr) {
      float4 qv = Qs4[rr][f];  // wave-uniform LDS broadcast
      a0[rr] += qv.x * kv0.x + qv.y * kv0.y + qv.z * kv0.z + qv.w * kv0.w;
      a1[rr] += qv.x * kv1.x + qv.y * kv1.y + qv.z * kv1.z + qv.w * kv1.w;
    }
  }
#pragma unroll
  for (int rr = 0; rr < 4; ++rr) {
    Sx[rr][t] += a0[rr] * 0.0625f;
    Sx[rr][t + 256] += a1[rr] * 0.0625f;
  }
  __syncthreads();

  // Phase C: wave w softmaxes row w and dots with vsum
  int w = t >> 6, l = t & 63;
  float m = -1e30f;
#pragma unroll
  for (int j = 0; j < 8; ++j) m = fmaxf(m, Sx[w][l + 64 * j]);
  for (int mm = 32; mm >= 1; mm >>= 1) m = fmaxf(m, __shfl_xor(m, mm));
  float se = 0.f, sv = 0.f;
#pragma unroll
  for (int j = 0; j < 8; ++j) {
    float ev = __expf(Sx[w][l + 64 * j] - m);
    se += ev;
    sv += ev * vs[l + 64 * j];
  }
  for (int mm = 32; mm >= 1; mm >>= 1) {
    se += __shfl_xor(se, mm);
    sv += __shfl_xor(sv, mm);
  }
  if (l == 0) out[rowbase + w] = sv / se;
}

// ---------------------------------------------------------------------------
extern "C" void kernel_launch(void* const* d_in, const int* in_sizes, int n_in,
                              void* d_out, int out_size, void* d_ws,
                              size_t ws_size, hipStream_t stream) {
  const float* F    = (const float*)d_in[0];
  const float* D    = (const float*)d_in[1];
  const float* Wq   = (const float*)d_in[2];
  const float* Wk   = (const float*)d_in[3];
  const float* Wv   = (const float*)d_in[4];
  const float* g_f  = (const float*)d_in[5];
  const float* b_f  = (const float*)d_in[6];
  const float* g_p  = (const float*)d_in[7];
  const float* b_p  = (const float*)d_in[8];
  const float* W_pt = (const float*)d_in[9];
  const float* b_pt = (const float*)d_in[10];
  const float* W_ph = (const float*)d_in[11];
  float* out = (float*)d_out;
  float* ws = (float*)d_ws;

  k1_fused<<<577, 256, 0, stream>>>(F, Wq, Wk, Wv, g_f, b_f, g_p, b_p, W_pt,
                                    b_pt, W_ph, ws);
  kb_bias_attn<<<512, 256, 0, stream>>>(D, ws, out);
}